// Round 1
// baseline (273.510 us; speedup 1.0000x reference)
//
#include <hip/hip_runtime.h>
#include <hip/hip_bf16.h>

typedef unsigned short us;
typedef __attribute__((ext_vector_type(8))) __bf16 bf16x8;
typedef __attribute__((ext_vector_type(4))) float f32x4;

#define MFMA16(a, b, c) __builtin_amdgcn_mfma_f32_16x16x32_bf16(a, b, c, 0, 0, 0)

static __device__ __forceinline__ us f2bf(float f) {
  __hip_bfloat16 h = __float2bfloat16(f);
  return __builtin_bit_cast(us, h);
}

// async global->LDS, 16B per lane; LDS dest is wave-uniform base + lane*16
static __device__ __forceinline__ void gll16(const us* g, us* l) {
  __builtin_amdgcn_global_load_lds((const __attribute__((address_space(1))) void*)g,
                                   (__attribute__((address_space(3))) void*)l,
                                   16, 0, 0);
}

// ---------------------------------------------------------------- casts ----
__global__ void cast_kernel(const float* __restrict__ in, us* __restrict__ out, int n4) {
  int i = blockIdx.x * blockDim.x + threadIdx.x;
  if (i >= n4) return;
  float4 v = ((const float4*)in)[i];
  ushort4 o;
  o.x = f2bf(v.x); o.y = f2bf(v.y); o.z = f2bf(v.z); o.w = f2bf(v.w);
  ((ushort4*)out)[i] = o;
}

// ------------------------------------------- GEMM1: qkv + RoPE + scatter ----
// A = xb [8192][1024], B = wqb [3072][1024] (B^T pattern: out[m][n]=sum_k A[m,k]B[n,k])
// epilogue: which=by/8 (0=q,1=k,2=v), h=by%8; q/k roped -> [b][h][t][128]; v -> vT [b][h][128][4096]
__global__ __launch_bounds__(256, 2)
void qkv_rope_kernel(const us* __restrict__ A, const us* __restrict__ B,
                     us* __restrict__ qb, us* __restrict__ kb, us* __restrict__ vtb) {
  __shared__ __align__(16) char smem_raw[128 * 132 * 4]; // union: sA+sB (32KB) / sC fp32 (67.5KB)
  us* sA = (us*)smem_raw;
  us* sB = sA + 128 * 64;
  float* sC = (float*)smem_raw;

  const int tid = threadIdx.x;
  const int lane = tid & 63;
  const int wave = tid >> 6;
  const int l15 = lane & 15;
  const int lq = lane >> 4;
  const int m0 = blockIdx.x * 128;
  const int n0 = blockIdx.y * 128;
  const int wm = (wave & 1) * 64;
  const int wn = (wave >> 1) * 64;

  f32x4 acc[4][4] = {};

  for (int k0 = 0; k0 < 1024; k0 += 64) {
    for (int i = 0; i < 4; ++i) {
      int c = wave * 4 + i;
      int P = c * 64 + lane;           // 16B slot index
      int row = P >> 3;                // 8 slots per 64-el row
      int cb = (P & 7) ^ (row & 7);    // xor-swizzle: physical slot holds logical col-block cb
      gll16(A + (size_t)(m0 + row) * 1024 + k0 + cb * 8, sA + c * 512);
      gll16(B + (size_t)(n0 + row) * 1024 + k0 + cb * 8, sB + c * 512);
    }
    __syncthreads();
#pragma unroll
    for (int kk = 0; kk < 64; kk += 32) {
      const int cbr = (kk + lq * 8) >> 3;
      bf16x8 av[4], bv[4];
#pragma unroll
      for (int mt = 0; mt < 4; ++mt) {
        int m = wm + mt * 16 + l15;
        av[mt] = *(const bf16x8*)(sA + (m * 8 + (cbr ^ (m & 7))) * 8);
      }
#pragma unroll
      for (int nt = 0; nt < 4; ++nt) {
        int n = wn + nt * 16 + l15;
        bv[nt] = *(const bf16x8*)(sB + (n * 8 + (cbr ^ (n & 7))) * 8);
      }
#pragma unroll
      for (int mt = 0; mt < 4; ++mt)
#pragma unroll
        for (int nt = 0; nt < 4; ++nt)
          acc[mt][nt] = MFMA16(av[mt], bv[nt], acc[mt][nt]);
    }
    __syncthreads();
  }

  // accumulators -> padded fp32 LDS tile (ld=132)
#pragma unroll
  for (int mt = 0; mt < 4; ++mt)
#pragma unroll
    for (int nt = 0; nt < 4; ++nt)
#pragma unroll
      for (int r = 0; r < 4; ++r) {
        int row = wm + mt * 16 + lq * 4 + r;
        int col = wn + nt * 16 + l15;
        sC[row * 132 + col] = acc[mt][nt][r];
      }
  __syncthreads();

  const int b = m0 >> 12;
  const int t0 = m0 & 4095;
  const int which = blockIdx.y >> 3;
  const int h = blockIdx.y & 7;

  if (which < 2) {
    // RoPE: out[d] = x[d]*cos(t*f) + rot[d]*sin(t*f); rot[d] = d<64 ? -x[d+64] : x[d-64]
    us* outp = (which == 0) ? qb : kb;
    for (int r = 0; r < 8; ++r) {
      int tl = (tid >> 4) + r * 16;
      int d0 = (tid & 15) * 8;
      int tg = t0 + tl;
      union { us u[8]; uint4 v; } tmp;
#pragma unroll
      for (int j = 0; j < 8; ++j) {
        int d = d0 + j;
        float xv = sC[tl * 132 + d];
        float xp = sC[tl * 132 + (d ^ 64)];
        float rot = (d < 64) ? -xp : xp;
        // inv_freq = 10000^-( (d&63)/64 ) = 2^-( (d&63) * log2(10000)/64 )
        float ang = (float)tg * exp2f((float)(d & 63) * -0.20762050593046014f);
        float sn, cs;
        sincosf(ang, &sn, &cs);
        tmp.u[j] = f2bf(xv * cs + rot * sn);
      }
      *(uint4*)(outp + ((size_t)((b * 8 + h) * 4096 + tg)) * 128 + d0) = tmp.v;
    }
  } else {
    // V transpose: vT[b][h][d][t]
    for (int r = 0; r < 8; ++r) {
      int d = (tid >> 4) + r * 16;
      int tl0 = (tid & 15) * 8;
      union { us u[8]; uint4 v; } tmp;
#pragma unroll
      for (int j = 0; j < 8; ++j)
        tmp.u[j] = f2bf(sC[(tl0 + j) * 132 + d]);
      *(uint4*)(vtb + ((size_t)((b * 8 + h) * 128 + d)) * 4096 + t0 + tl0) = tmp.v;
    }
  }
}

// --------------------------------------------------- flash attention --------
// grid (qt=32, h=8, b=2); 128 q-rows/block; window: j in [i-512, i]
__global__ __launch_bounds__(256, 1)
void flash_kernel(const us* __restrict__ qg, const us* __restrict__ kg,
                  const us* __restrict__ vg, us* __restrict__ ao) {
  __shared__ us sQ[128 * 128];   // [t][d] swizzled
  __shared__ us sK[128 * 128];   // [j][d] swizzled
  __shared__ us sV[128 * 128];   // V^T tile [d][j] swizzled
  __shared__ us sP[128 * 136];   // padded, VALU-written

  const int tid = threadIdx.x;
  const int lane = tid & 63;
  const int wave = tid >> 6;
  const int l15 = lane & 15;
  const int lq = lane >> 4;
  const int qt = blockIdx.x;
  const int h = blockIdx.y;
  const int b = blockIdx.z;
  const int t0 = qt * 128;
  const size_t bh = (size_t)(b * 8 + h);

  for (int i = 0; i < 8; ++i) {
    int c = wave * 8 + i;
    int P = c * 64 + lane;
    int row = P >> 4;                 // 16 slots per 128-el row
    int cb = (P & 15) ^ (row & 15);
    gll16(qg + (bh * 4096 + t0 + row) * 128 + cb * 8, sQ + c * 512);
  }

  float m_st[2][4], l_st[2][4];
  f32x4 o[2][8] = {};
#pragma unroll
  for (int mt = 0; mt < 2; ++mt)
#pragma unroll
    for (int r = 0; r < 4; ++r) { m_st[mt][r] = -3.0e38f; l_st[mt][r] = 0.0f; }

  const int wm = wave * 32;
  const float scale = 0.08838834764831845f; // 1/sqrt(128)
  int jt0 = qt - 4; if (jt0 < 0) jt0 = 0;

  for (int jt = jt0; jt <= qt; ++jt) {
    const int tj0 = jt * 128;
    for (int i = 0; i < 8; ++i) {
      int c = wave * 8 + i;
      int P = c * 64 + lane;
      int row = P >> 4;
      int cb = (P & 15) ^ (row & 15);
      gll16(kg + (bh * 4096 + tj0 + row) * 128 + cb * 8, sK + c * 512);
      gll16(vg + (bh * 128 + row) * 4096 + tj0 + cb * 8, sV + c * 512);
    }
    __syncthreads();

    // S = Q K^T  (each wave: 32 q-rows x 128 keys)
    f32x4 s[2][8] = {};
#pragma unroll
    for (int kk = 0; kk < 128; kk += 32) {
      const int ko = kk + lq * 8;
      const int cbr = ko >> 3;
      bf16x8 aq[2];
#pragma unroll
      for (int mt = 0; mt < 2; ++mt) {
        int m = wm + mt * 16 + l15;
        aq[mt] = *(const bf16x8*)(sQ + (m * 16 + (cbr ^ (m & 15))) * 8);
      }
#pragma unroll
      for (int nt = 0; nt < 8; ++nt) {
        int n = nt * 16 + l15;
        bf16x8 bk = *(const bf16x8*)(sK + (n * 16 + (cbr ^ (n & 15))) * 8);
#pragma unroll
        for (int mt = 0; mt < 2; ++mt)
          s[mt][nt] = MFMA16(aq[mt], bk, s[mt][nt]);
      }
    }

    // online softmax; rows of state regs align with C-layout rows
#pragma unroll
    for (int mt = 0; mt < 2; ++mt) {
#pragma unroll
      for (int r = 0; r < 4; ++r) {
        const int rowl = wm + mt * 16 + lq * 4 + r;
        const int ig = t0 + rowl;
        float pv[8];
        float mx = -3.0e38f;
#pragma unroll
        for (int nt = 0; nt < 8; ++nt) {
          int jg = tj0 + nt * 16 + l15;
          bool keep = (jg <= ig) && (jg + 512 >= ig);
          float v = keep ? s[mt][nt][r] * scale : -3.0e38f;
          pv[nt] = v;
          mx = fmaxf(mx, v);
        }
#pragma unroll
        for (int off = 1; off < 16; off <<= 1) mx = fmaxf(mx, __shfl_xor(mx, off, 64));
        const float mnew = fmaxf(m_st[mt][r], mx);
        const float alpha = __expf(m_st[mt][r] - mnew); // finite sentinels: no NaN
        float rs = 0.0f;
#pragma unroll
        for (int nt = 0; nt < 8; ++nt) {
          float p = (pv[nt] > -1.0e38f) ? __expf(pv[nt] - mnew) : 0.0f;
          rs += p;
          sP[rowl * 136 + nt * 16 + l15] = f2bf(p); // own rows only: wave-internal RAW
        }
#pragma unroll
        for (int off = 1; off < 16; off <<= 1) rs += __shfl_xor(rs, off, 64);
        m_st[mt][r] = mnew;
        l_st[mt][r] = l_st[mt][r] * alpha + rs;
#pragma unroll
        for (int dt = 0; dt < 8; ++dt) o[mt][dt][r] *= alpha;
      }
    }

    // O += P V  (A = sP own rows, B = sV = V^T)
#pragma unroll
    for (int kk = 0; kk < 128; kk += 32) {
      const int ko = kk + lq * 8;
      const int cbr = ko >> 3;
      bf16x8 ap[2];
#pragma unroll
      for (int mt = 0; mt < 2; ++mt) {
        int m = wm + mt * 16 + l15;
        ap[mt] = *(const bf16x8*)(sP + m * 136 + ko);
      }
#pragma unroll
      for (int dt = 0; dt < 8; ++dt) {
        int dd = dt * 16 + l15;
        bf16x8 bv = *(const bf16x8*)(sV + (dd * 16 + (cbr ^ (dd & 15))) * 8);
#pragma unroll
        for (int mt = 0; mt < 2; ++mt)
          o[mt][dt] = MFMA16(ap[mt], bv, o[mt][dt]);
      }
    }
    __syncthreads(); // protect sK/sV restage
  }

  // epilogue: O/l -> ao [b*4096+t][h*128+d] bf16
#pragma unroll
  for (int mt = 0; mt < 2; ++mt)
#pragma unroll
    for (int r = 0; r < 4; ++r) {
      const float inv = 1.0f / l_st[mt][r];
      const int rowl = wm + mt * 16 + lq * 4 + r;
      const size_t base = ((size_t)b * 4096 + t0 + rowl) * 1024 + h * 128;
#pragma unroll
      for (int dt = 0; dt < 8; ++dt)
        ao[base + dt * 16 + l15] = f2bf(o[mt][dt][r] * inv);
    }
}

// ------------------------------------------------ GEMM3: out = ao @ w_o^T ---
__global__ __launch_bounds__(256, 2)
void out_proj_kernel(const us* __restrict__ A, const us* __restrict__ B, float* __restrict__ C) {
  __shared__ us sA[128 * 64];
  __shared__ us sB[128 * 64];
  const int tid = threadIdx.x;
  const int lane = tid & 63;
  const int wave = tid >> 6;
  const int l15 = lane & 15;
  const int lq = lane >> 4;
  const int m0 = blockIdx.x * 128;
  const int n0 = blockIdx.y * 128;
  const int wm = (wave & 1) * 64;
  const int wn = (wave >> 1) * 64;
  f32x4 acc[4][4] = {};
  for (int k0 = 0; k0 < 1024; k0 += 64) {
    for (int i = 0; i < 4; ++i) {
      int c = wave * 4 + i;
      int P = c * 64 + lane;
      int row = P >> 3;
      int cb = (P & 7) ^ (row & 7);
      gll16(A + (size_t)(m0 + row) * 1024 + k0 + cb * 8, sA + c * 512);
      gll16(B + (size_t)(n0 + row) * 1024 + k0 + cb * 8, sB + c * 512);
    }
    __syncthreads();
#pragma unroll
    for (int kk = 0; kk < 64; kk += 32) {
      const int cbr = (kk + lq * 8) >> 3;
      bf16x8 av[4], bv[4];
#pragma unroll
      for (int mt = 0; mt < 4; ++mt) {
        int m = wm + mt * 16 + l15;
        av[mt] = *(const bf16x8*)(sA + (m * 8 + (cbr ^ (m & 7))) * 8);
      }
#pragma unroll
      for (int nt = 0; nt < 4; ++nt) {
        int n = wn + nt * 16 + l15;
        bv[nt] = *(const bf16x8*)(sB + (n * 8 + (cbr ^ (n & 7))) * 8);
      }
#pragma unroll
      for (int mt = 0; mt < 4; ++mt)
#pragma unroll
        for (int nt = 0; nt < 4; ++nt)
          acc[mt][nt] = MFMA16(av[mt], bv[nt], acc[mt][nt]);
    }
    __syncthreads();
  }
#pragma unroll
  for (int mt = 0; mt < 4; ++mt)
#pragma unroll
    for (int nt = 0; nt < 4; ++nt)
#pragma unroll
      for (int r = 0; r < 4; ++r)
        C[(size_t)(m0 + wm + mt * 16 + lq * 4 + r) * 1024 + (n0 + wn + nt * 16 + l15)] =
            acc[mt][nt][r];
}

// ---------------------------------------------------------------- launch ----
extern "C" void kernel_launch(void* const* d_in, const int* in_sizes, int n_in,
                              void* d_out, int out_size, void* d_ws, size_t ws_size,
                              hipStream_t stream) {
  const float* x     = (const float*)d_in[0];  // [2,4096,1024]
  const float* w_qkv = (const float*)d_in[1];  // [3072,1024]
  const float* w_o   = (const float*)d_in[2];  // [1024,1024]
  float* out = (float*)d_out;                  // [2,4096,1024] fp32

  us* xb  = (us*)d_ws;                          // 8192*1024
  us* wqb = xb  + (size_t)8192 * 1024;          // 3072*1024
  us* wob = wqb + (size_t)3072 * 1024;          // 1024*1024
  us* qb  = wob + (size_t)1024 * 1024;          // [2][8][4096][128]
  us* kb  = qb  + (size_t)2 * 8 * 4096 * 128;
  us* vtb = kb  + (size_t)2 * 8 * 4096 * 128;   // [2][8][128][4096]
  us* aob = vtb + (size_t)2 * 8 * 4096 * 128;   // 8192*1024

  cast_kernel<<<8192, 256, 0, stream>>>(x, xb, 8192 * 1024 / 4);
  cast_kernel<<<3072, 256, 0, stream>>>(w_qkv, wqb, 3072 * 1024 / 4);
  cast_kernel<<<1024, 256, 0, stream>>>(w_o, wob, 1024 * 1024 / 4);
  qkv_rope_kernel<<<dim3(64, 24), 256, 0, stream>>>(xb, wqb, qb, kb, vtb);
  flash_kernel<<<dim3(32, 8, 2), 256, 0, stream>>>(qb, kb, vtb, aob);
  out_proj_kernel<<<dim3(64, 8), 256, 0, stream>>>(aob, wob, out);
}